// Round 5
// baseline (3385.012 us; speedup 1.0000x reference)
//
#include <hip/hip_runtime.h>

#define NSs 100000
#define NIi 20000
#define DD  128
#define E1e 600000
#define E2e 500000

typedef __attribute__((ext_vector_type(8))) __bf16 bf16x8;
typedef __attribute__((ext_vector_type(4))) __bf16 bf16x4;
typedef __attribute__((ext_vector_type(4))) float  floatx4;

// ---------------------------------------------------------------------------
// Scatter: for each edge e, agg[dst[e]] += x[src[e]] (f32 atomics), cnt[dst]++
// One wave (64 lanes) per edge, 2 f32 columns per lane.
// ---------------------------------------------------------------------------
__global__ __launch_bounds__(256) void scatter_kernel(
    const float* __restrict__ x,
    const int* __restrict__ src,
    const int* __restrict__ dst,
    float* __restrict__ agg,
    float* __restrict__ cnt,   // may be null (SimpleConv: no mean)
    int E)
{
    long gid = (long)blockIdx.x * blockDim.x + threadIdx.x;
    int e    = (int)(gid >> 6);
    int lane = (int)(gid & 63);
    if (e >= E) return;
    int s = src[e];
    int d = dst[e];
    float2 v = *(const float2*)(x + (size_t)s * DD + lane * 2);
    float* ap = agg + (size_t)d * DD + lane * 2;
    unsafeAtomicAdd(ap,     v.x);
    unsafeAtomicAdd(ap + 1, v.y);
    if (cnt != nullptr && lane == 0) unsafeAtomicAdd(cnt + d, 1.0f);
}

// ---------------------------------------------------------------------------
// Convert the 5 weight tensors (each L*D*D = 32768 f32) to packed bf16.
// Layout: [Wl_ri | Wr_ri | Wl_rs | Wr_rs | W_p], each slot 32768 elements.
// ---------------------------------------------------------------------------
__global__ __launch_bounds__(256) void cvt_weights(
    const float* __restrict__ a, const float* __restrict__ b,
    const float* __restrict__ c, const float* __restrict__ d,
    const float* __restrict__ e, __bf16* __restrict__ out)
{
    int i = blockIdx.x * 256 + threadIdx.x;   // grid covers 5*32768
    const float* srcs[5] = {a, b, c, d, e};
    int which = i >> 15;
    int idx   = i & 32767;
    out[i] = (__bf16)srcs[which][idx];
}

// ---------------------------------------------------------------------------
// Student GEMM (MFMA): out = 0.5*( (agg/cnt)@Wl.T + xs@Wr.T + sim@Wp.T + bl + bp )
// 64 rows/block, 4 waves, wave = 16 rows x 128 cols via mfma 16x16x32.
// NOTE: in layer 2, xs aliases out (same d_out rows). Each block reads only
// rows it writes; reads complete (LDS stage + syncthreads) before writes.
// ---------------------------------------------------------------------------
#define BM 64

__global__ __launch_bounds__(256) void gemm_stu(
    const float*  __restrict__ agg,
    const float*  __restrict__ cnt,
    const float*  xs,                 // may alias out!
    const float*  __restrict__ sim,
    const __bf16* __restrict__ Wl,
    const __bf16* __restrict__ Wr,
    const __bf16* __restrict__ Wp,
    const float*  __restrict__ bl,
    const float*  __restrict__ bp,
    float* out,
    int M)
{
    __shared__ __align__(16) __bf16 As[3][BM][136];  // +8 pad
    int tid  = threadIdx.x;
    int row0 = blockIdx.x * BM;

    for (int i = tid; i < BM * 32; i += 256) {
        int r  = i >> 5;
        int c4 = (i & 31) << 2;
        int gr = row0 + r; if (gr > M - 1) gr = M - 1;
        floatx4 a = *(const floatx4*)(agg + (size_t)gr * DD + c4);
        float inv = 1.0f / fmaxf(cnt[gr], 1.0f);
        bf16x4 o0 = { (__bf16)(a.x * inv), (__bf16)(a.y * inv),
                      (__bf16)(a.z * inv), (__bf16)(a.w * inv) };
        *(bf16x4*)&As[0][r][c4] = o0;
        floatx4 xv = *(const floatx4*)(xs + (size_t)gr * DD + c4);
        bf16x4 o1 = { (__bf16)xv.x, (__bf16)xv.y, (__bf16)xv.z, (__bf16)xv.w };
        *(bf16x4*)&As[1][r][c4] = o1;
        floatx4 s = *(const floatx4*)(sim + (size_t)gr * DD + c4);
        bf16x4 o2 = { (__bf16)s.x, (__bf16)s.y, (__bf16)s.z, (__bf16)s.w };
        *(bf16x4*)&As[2][r][c4] = o2;
    }
    __syncthreads();

    int lane = tid & 63;
    int wv   = tid >> 6;
    int rb   = wv * 16;
    int mrow = lane & 15;
    int koff = (lane >> 4) * 8;

    floatx4 acc[8];
#pragma unroll
    for (int i = 0; i < 8; i++) acc[i] = (floatx4){0.f, 0.f, 0.f, 0.f};

    const __bf16* Ws[3] = {Wl, Wr, Wp};
#pragma unroll
    for (int m = 0; m < 3; m++) {
#pragma unroll
        for (int kc = 0; kc < 4; kc++) {
            bf16x8 afrag = *(const bf16x8*)&As[m][rb + mrow][kc * 32 + koff];
#pragma unroll
            for (int ct = 0; ct < 8; ct++) {
                bf16x8 bfrag = *(const bf16x8*)(Ws[m] + (size_t)(ct * 16 + mrow) * DD + kc * 32 + koff);
                acc[ct] = __builtin_amdgcn_mfma_f32_16x16x32_bf16(afrag, bfrag, acc[ct], 0, 0, 0);
            }
        }
    }

    int orow = rb + (lane >> 4) * 4;
#pragma unroll
    for (int ct = 0; ct < 8; ct++) {
        int col  = ct * 16 + mrow;
        float bb = bl[col] + bp[col];
#pragma unroll
        for (int r = 0; r < 4; r++) {
            int grow = row0 + orow + r;
            if (grow < M)
                out[(size_t)grow * DD + col] = 0.5f * (acc[ct][r] + bb);
        }
    }
}

// ---------------------------------------------------------------------------
// Item GEMM (MFMA): pre = (agg/cnt)@Wl.T + xi@Wr.T + bl ; out = elu(pre) (f32)
// ---------------------------------------------------------------------------
__global__ __launch_bounds__(256) void gemm_item(
    const float*  __restrict__ agg,
    const float*  __restrict__ cnt,
    const float*  __restrict__ xi,
    const __bf16* __restrict__ Wl,
    const __bf16* __restrict__ Wr,
    const float*  __restrict__ bl,
    float* __restrict__ out,
    int M)
{
    __shared__ __align__(16) __bf16 As[2][BM][136];
    int tid  = threadIdx.x;
    int row0 = blockIdx.x * BM;

    for (int i = tid; i < BM * 32; i += 256) {
        int r  = i >> 5;
        int c4 = (i & 31) << 2;
        int gr = row0 + r; if (gr > M - 1) gr = M - 1;
        floatx4 a = *(const floatx4*)(agg + (size_t)gr * DD + c4);
        float inv = 1.0f / fmaxf(cnt[gr], 1.0f);
        bf16x4 o0 = { (__bf16)(a.x * inv), (__bf16)(a.y * inv),
                      (__bf16)(a.z * inv), (__bf16)(a.w * inv) };
        *(bf16x4*)&As[0][r][c4] = o0;
        floatx4 xv = *(const floatx4*)(xi + (size_t)gr * DD + c4);
        bf16x4 o1 = { (__bf16)xv.x, (__bf16)xv.y, (__bf16)xv.z, (__bf16)xv.w };
        *(bf16x4*)&As[1][r][c4] = o1;
    }
    __syncthreads();

    int lane = tid & 63;
    int wv   = tid >> 6;
    int rb   = wv * 16;
    int mrow = lane & 15;
    int koff = (lane >> 4) * 8;

    floatx4 acc[8];
#pragma unroll
    for (int i = 0; i < 8; i++) acc[i] = (floatx4){0.f, 0.f, 0.f, 0.f};

    const __bf16* Ws[2] = {Wl, Wr};
#pragma unroll
    for (int m = 0; m < 2; m++) {
#pragma unroll
        for (int kc = 0; kc < 4; kc++) {
            bf16x8 afrag = *(const bf16x8*)&As[m][rb + mrow][kc * 32 + koff];
#pragma unroll
            for (int ct = 0; ct < 8; ct++) {
                bf16x8 bfrag = *(const bf16x8*)(Ws[m] + (size_t)(ct * 16 + mrow) * DD + kc * 32 + koff);
                acc[ct] = __builtin_amdgcn_mfma_f32_16x16x32_bf16(afrag, bfrag, acc[ct], 0, 0, 0);
            }
        }
    }

    int orow = rb + (lane >> 4) * 4;
#pragma unroll
    for (int ct = 0; ct < 8; ct++) {
        int col = ct * 16 + mrow;
        float bb = bl[col];
#pragma unroll
        for (int r = 0; r < 4; r++) {
            int grow = row0 + orow + r;
            if (grow < M) {
                float v = acc[ct][r] + bb;
                v = (v > 0.f) ? v : expm1f(v);
                out[(size_t)grow * DD + col] = v;
            }
        }
    }
}

// ---------------------------------------------------------------------------
// BN column stats: one block per column n, reduce mean & rsqrt(var+eps)
// ---------------------------------------------------------------------------
__global__ __launch_bounds__(256) void bn_stats(
    const float* __restrict__ x, int M,
    float* __restrict__ mout, float* __restrict__ rout)
{
    int n   = blockIdx.x;
    int tid = threadIdx.x;
    float s = 0.f, s2 = 0.f;
    for (int i = tid; i < M; i += 256) {
        float v = x[(size_t)i * DD + n];
        s += v; s2 += v * v;
    }
    __shared__ float ls[256], ls2[256];
    ls[tid] = s; ls2[tid] = s2;
    __syncthreads();
    for (int ofs = 128; ofs > 0; ofs >>= 1) {
        if (tid < ofs) { ls[tid] += ls[tid + ofs]; ls2[tid] += ls2[tid + ofs]; }
        __syncthreads();
    }
    if (tid == 0) {
        float m = ls[0] / (float)M;
        float v = ls2[0] / (float)M - m * m;
        mout[n] = m;
        rout[n] = rsqrtf(v + 1e-5f);
    }
}

// ---------------------------------------------------------------------------
// BN normalize: out = (x - m)*rstd*g + b   (f32 out)
// ---------------------------------------------------------------------------
__global__ __launch_bounds__(256) void bn_norm(
    const float* __restrict__ x,
    const float* __restrict__ m,
    const float* __restrict__ r,
    const float* __restrict__ g,
    const float* __restrict__ b,
    float* __restrict__ out,
    int M)
{
    int i = blockIdx.x * 256 + threadIdx.x;
    if (i >= M * 32) return;
    int row = i >> 5;
    int c4  = (i & 31) << 2;
    floatx4 v = *(const floatx4*)(x + (size_t)row * DD + c4);
    floatx4 o;
    o.x = (v.x - m[c4 + 0]) * r[c4 + 0] * g[c4 + 0] + b[c4 + 0];
    o.y = (v.y - m[c4 + 1]) * r[c4 + 1] * g[c4 + 1] + b[c4 + 1];
    o.z = (v.z - m[c4 + 2]) * r[c4 + 2] * g[c4 + 2] + b[c4 + 2];
    o.w = (v.w - m[c4 + 3]) * r[c4 + 3] * g[c4 + 3] + b[c4 + 3];
    *(floatx4*)(out + (size_t)row * DD + c4) = o;
}

// ---------------------------------------------------------------------------
extern "C" void kernel_launch(void* const* d_in, const int* in_sizes, int n_in,
                              void* d_out, int out_size, void* d_ws, size_t ws_size,
                              hipStream_t stream)
{
    const float* x_student = (const float*)d_in[0];
    const float* x_item    = (const float*)d_in[1];
    const float* Wl_ri     = (const float*)d_in[2];
    const float* bl_ri     = (const float*)d_in[3];
    const float* Wr_ri     = (const float*)d_in[4];
    const float* Wl_rs     = (const float*)d_in[5];
    const float* bl_rs     = (const float*)d_in[6];
    const float* Wr_rs     = (const float*)d_in[7];
    const float* W_p       = (const float*)d_in[8];
    const float* b_p       = (const float*)d_in[9];
    const float* bn_g      = (const float*)d_in[10];
    const float* bn_b      = (const float*)d_in[11];
    const int* resp_src = (const int*)d_in[12];
    const int* resp_dst = (const int*)d_in[13];
    const int* rev_src  = (const int*)d_in[14];
    const int* rev_dst  = (const int*)d_in[15];
    const int* prec_src = (const int*)d_in[16];
    const int* prec_dst = (const int*)d_in[17];

    // ---- workspace (~124 MB; layer-1 f32 state lives in d_out exactly) ----
    char* ws = (char*)d_ws;
    size_t off = 0;
    auto alloc = [&](size_t bytes) -> void* {
        void* p = ws + off;
        off += (bytes + 1023) & ~(size_t)1023;
        return p;
    };
    float* agg_s = (float*)alloc((size_t)NSs * DD * 4);   // 51.2 MB
    float* sim_s = (float*)alloc((size_t)NSs * DD * 4);   // 51.2 MB
    float* agg_i = (float*)alloc((size_t)NIi * DD * 4);   // 10.24 MB
    float* cnt_s = (float*)alloc((size_t)NSs * 4);
    float* cnt_i = (float*)alloc((size_t)NIi * 4);
    size_t zero_bytes = off;                               // zeroed per layer
    float*  xi_tmp = (float*)alloc((size_t)NIi * DD * 4);  // 10.24 MB
    __bf16* wbf    = (__bf16*)alloc((size_t)5 * 32768 * 2);
    float*  bn_m   = (float*)alloc(512);
    float*  bn_r   = (float*)alloc(512);
    (void)ws_size; (void)in_sizes; (void)n_in; (void)out_size;

    // Output is FLOAT32. Layer-1 state stored in d_out (f32, exact fit),
    // overwritten in-place by layer 2.
    float* out_xi = (float*)d_out;                    // xi_1 then xi_2
    float* out_xs = out_xi + (size_t)NIi * DD;        // xs_1 then xs_2

    const int sc_blocks1 = (int)(((long)E1e * 64 + 255) / 256);
    const int sc_blocks2 = (int)(((long)E2e * 64 + 255) / 256);
    const int gi_blocks  = (NIi + BM - 1) / BM;
    const int gs_blocks  = (NSs + BM - 1) / BM;
    const int bnn_blocks = (NIi * 32 + 255) / 256;

    // Packed bf16 weights: slots [Wl_ri|Wr_ri|Wl_rs|Wr_rs|W_p], 32768 each
    cvt_weights<<<640, 256, 0, stream>>>(Wl_ri, Wr_ri, Wl_rs, Wr_rs, W_p, wbf);
    __bf16* wb_l_ri = wbf + 0 * 32768;
    __bf16* wb_r_ri = wbf + 1 * 32768;
    __bf16* wb_l_rs = wbf + 2 * 32768;
    __bf16* wb_r_rs = wbf + 3 * 32768;
    __bf16* wb_p    = wbf + 4 * 32768;

    for (int l = 0; l < 2; l++) {
        const float* xs_cur = (l == 0) ? x_student : out_xs;
        const float* xi_cur = (l == 0) ? x_item    : out_xi;
        size_t wOfs = (size_t)l * DD * DD;
        size_t bOfs = (size_t)l * DD;

        hipMemsetAsync(ws, 0, zero_bytes, stream);

        scatter_kernel<<<sc_blocks1, 256, 0, stream>>>(xs_cur, resp_src, resp_dst, agg_i, cnt_i, E1e);
        scatter_kernel<<<sc_blocks1, 256, 0, stream>>>(xi_cur, rev_src,  rev_dst,  agg_s, cnt_s, E1e);
        scatter_kernel<<<sc_blocks2, 256, 0, stream>>>(xs_cur, prec_src, prec_dst, sim_s, nullptr, E2e);

        // item path: reads xi_cur fully before bn_norm overwrites out_xi
        gemm_item<<<gi_blocks, 256, 0, stream>>>(agg_i, cnt_i, xi_cur,
                                                 wb_l_ri + wOfs, wb_r_ri + wOfs, bl_ri + bOfs,
                                                 xi_tmp, NIi);
        bn_stats<<<DD, 256, 0, stream>>>(xi_tmp, NIi, bn_m, bn_r);
        bn_norm<<<bnn_blocks, 256, 0, stream>>>(xi_tmp, bn_m, bn_r,
                                                bn_g + bOfs, bn_b + bOfs, out_xi, NIi);

        // student path: in layer 2 xs_cur aliases out_xs (block-local rows only)
        gemm_stu<<<gs_blocks, 256, 0, stream>>>(agg_s, cnt_s, xs_cur, sim_s,
                                                wb_l_rs + wOfs, wb_r_rs + wOfs, wb_p + wOfs,
                                                bl_rs + bOfs, b_p + bOfs,
                                                out_xs, NSs);
    }
}

// Round 6
// 986.255 us; speedup vs baseline: 3.4322x; 3.4322x over previous
//
#include <hip/hip_runtime.h>

#define NSs 100000
#define NIi 20000
#define DD  128
#define E1e 600000
#define E2e 500000

typedef __attribute__((ext_vector_type(8))) __bf16 bf16x8;
typedef __attribute__((ext_vector_type(4))) __bf16 bf16x4;
typedef __attribute__((ext_vector_type(4))) float  floatx4;

// ===========================================================================
// CSR build (once per call, reused by both layers).
// Segments are allocated in arbitrary order via wave-level ticketing — each
// dst d owns eidx[start[d] .. end[d]).
// ===========================================================================
__global__ __launch_bounds__(256) void hist_kernel(
    const int* __restrict__ dst, int* __restrict__ cnt, int E)
{
    int e = blockIdx.x * 256 + threadIdx.x;
    if (e < E) atomicAdd(cnt + dst[e], 1);
}

__global__ __launch_bounds__(256) void ticket_kernel(
    const int* __restrict__ cnt, int* __restrict__ start,
    int* __restrict__ fill, int* __restrict__ total, int n)
{
    int i    = blockIdx.x * 256 + threadIdx.x;
    int lane = threadIdx.x & 63;
    int c    = (i < n) ? cnt[i] : 0;
    int sum  = c;                       // wave-inclusive scan
#pragma unroll
    for (int ofs = 1; ofs < 64; ofs <<= 1) {
        int up = __shfl_up(sum, ofs, 64);
        if (lane >= ofs) sum += up;
    }
    int wtot = __shfl(sum, 63, 64);
    int base = 0;
    if (lane == 63) base = atomicAdd(total, wtot);
    base = __shfl(base, 63, 64);
    if (i < n) {
        int st = base + sum - c;        // exclusive within wave
        start[i] = st;
        fill[i]  = st;
    }
}

__global__ __launch_bounds__(256) void fill_kernel(
    const int* __restrict__ src, const int* __restrict__ dst,
    int* __restrict__ fill, int* __restrict__ eidx, int E)
{
    int e = blockIdx.x * 256 + threadIdx.x;
    if (e < E) {
        int pos = atomicAdd(fill + dst[e], 1);
        eidx[pos] = src[e];
    }
}

// ===========================================================================
// Gather-aggregate: one wave per dst row; lane owns 2 columns (512 B row
// loads, coalesced). MEAN divides by neighbor count (clip 1). No atomics,
// no pre-zeroing (every row written).
// ===========================================================================
template <bool MEAN>
__global__ __launch_bounds__(256) void gather_kernel(
    const float* __restrict__ x,
    const int* __restrict__ start,
    const int* __restrict__ end,
    const int* __restrict__ eidx,
    float* __restrict__ agg,
    int n_dst)
{
    long gid = (long)blockIdx.x * 256 + threadIdx.x;
    int d    = (int)(gid >> 6);
    int lane = (int)(gid & 63);
    if (d >= n_dst) return;
    int s0 = start[d], s1 = end[d];
    float2 acc = {0.f, 0.f};
    int i = s0;
    for (; i + 1 < s1; i += 2) {            // 2-way unroll: overlap row loads
        int r0 = eidx[i], r1 = eidx[i + 1];
        float2 v0 = *(const float2*)(x + (size_t)r0 * DD + lane * 2);
        float2 v1 = *(const float2*)(x + (size_t)r1 * DD + lane * 2);
        acc.x += v0.x + v1.x;
        acc.y += v0.y + v1.y;
    }
    if (i < s1) {
        int r0 = eidx[i];
        float2 v0 = *(const float2*)(x + (size_t)r0 * DD + lane * 2);
        acc.x += v0.x;
        acc.y += v0.y;
    }
    if (MEAN) {
        int c = s1 - s0;
        float inv = 1.0f / (float)(c > 1 ? c : 1);
        acc.x *= inv;
        acc.y *= inv;
    }
    *(float2*)(agg + (size_t)d * DD + lane * 2) = acc;
}

// ---------------------------------------------------------------------------
// Weights f32 → packed bf16: [Wl_ri | Wr_ri | Wl_rs | Wr_rs | W_p] × 32768.
// ---------------------------------------------------------------------------
__global__ __launch_bounds__(256) void cvt_weights(
    const float* __restrict__ a, const float* __restrict__ b,
    const float* __restrict__ c, const float* __restrict__ d,
    const float* __restrict__ e, __bf16* __restrict__ out)
{
    int i = blockIdx.x * 256 + threadIdx.x;   // grid covers 5*32768
    const float* srcs[5] = {a, b, c, d, e};
    int which = i >> 15;
    int idx   = i & 32767;
    out[i] = (__bf16)srcs[which][idx];
}

// ===========================================================================
// Student GEMM (MFMA): out = 0.5*( agg@Wl.T + xs@Wr.T + sim@Wp.T + bl + bp )
// agg arrives pre-averaged. 64 rows/block, 4 waves, mfma 16x16x32.
// Layer 2: xs aliases out (block reads only its own rows; LDS stage +
// syncthreads completes before writes).
// ===========================================================================
#define BM 64

__global__ __launch_bounds__(256) void gemm_stu(
    const float*  __restrict__ agg,
    const float*  xs,                 // may alias out!
    const float*  __restrict__ sim,
    const __bf16* __restrict__ Wl,
    const __bf16* __restrict__ Wr,
    const __bf16* __restrict__ Wp,
    const float*  __restrict__ bl,
    const float*  __restrict__ bp,
    float* out,
    int M)
{
    __shared__ __align__(16) __bf16 As[3][BM][136];  // +8 pad
    int tid  = threadIdx.x;
    int row0 = blockIdx.x * BM;

    for (int i = tid; i < BM * 32; i += 256) {
        int r  = i >> 5;
        int c4 = (i & 31) << 2;
        int gr = row0 + r; if (gr > M - 1) gr = M - 1;
        floatx4 a = *(const floatx4*)(agg + (size_t)gr * DD + c4);
        bf16x4 o0 = { (__bf16)a.x, (__bf16)a.y, (__bf16)a.z, (__bf16)a.w };
        *(bf16x4*)&As[0][r][c4] = o0;
        floatx4 xv = *(const floatx4*)(xs + (size_t)gr * DD + c4);
        bf16x4 o1 = { (__bf16)xv.x, (__bf16)xv.y, (__bf16)xv.z, (__bf16)xv.w };
        *(bf16x4*)&As[1][r][c4] = o1;
        floatx4 s = *(const floatx4*)(sim + (size_t)gr * DD + c4);
        bf16x4 o2 = { (__bf16)s.x, (__bf16)s.y, (__bf16)s.z, (__bf16)s.w };
        *(bf16x4*)&As[2][r][c4] = o2;
    }
    __syncthreads();

    int lane = tid & 63;
    int wv   = tid >> 6;
    int rb   = wv * 16;
    int mrow = lane & 15;
    int koff = (lane >> 4) * 8;

    floatx4 acc[8];
#pragma unroll
    for (int i = 0; i < 8; i++) acc[i] = (floatx4){0.f, 0.f, 0.f, 0.f};

    const __bf16* Ws[3] = {Wl, Wr, Wp};
#pragma unroll
    for (int m = 0; m < 3; m++) {
#pragma unroll
        for (int kc = 0; kc < 4; kc++) {
            bf16x8 afrag = *(const bf16x8*)&As[m][rb + mrow][kc * 32 + koff];
#pragma unroll
            for (int ct = 0; ct < 8; ct++) {
                bf16x8 bfrag = *(const bf16x8*)(Ws[m] + (size_t)(ct * 16 + mrow) * DD + kc * 32 + koff);
                acc[ct] = __builtin_amdgcn_mfma_f32_16x16x32_bf16(afrag, bfrag, acc[ct], 0, 0, 0);
            }
        }
    }

    int orow = rb + (lane >> 4) * 4;
#pragma unroll
    for (int ct = 0; ct < 8; ct++) {
        int col  = ct * 16 + mrow;
        float bb = bl[col] + bp[col];
#pragma unroll
        for (int r = 0; r < 4; r++) {
            int grow = row0 + orow + r;
            if (grow < M)
                out[(size_t)grow * DD + col] = 0.5f * (acc[ct][r] + bb);
        }
    }
}

// ---------------------------------------------------------------------------
// Item GEMM (MFMA): pre = agg@Wl.T + xi@Wr.T + bl ; out = elu(pre) (f32)
// ---------------------------------------------------------------------------
__global__ __launch_bounds__(256) void gemm_item(
    const float*  __restrict__ agg,
    const float*  __restrict__ xi,
    const __bf16* __restrict__ Wl,
    const __bf16* __restrict__ Wr,
    const float*  __restrict__ bl,
    float* __restrict__ out,
    int M)
{
    __shared__ __align__(16) __bf16 As[2][BM][136];
    int tid  = threadIdx.x;
    int row0 = blockIdx.x * BM;

    for (int i = tid; i < BM * 32; i += 256) {
        int r  = i >> 5;
        int c4 = (i & 31) << 2;
        int gr = row0 + r; if (gr > M - 1) gr = M - 1;
        floatx4 a = *(const floatx4*)(agg + (size_t)gr * DD + c4);
        bf16x4 o0 = { (__bf16)a.x, (__bf16)a.y, (__bf16)a.z, (__bf16)a.w };
        *(bf16x4*)&As[0][r][c4] = o0;
        floatx4 xv = *(const floatx4*)(xi + (size_t)gr * DD + c4);
        bf16x4 o1 = { (__bf16)xv.x, (__bf16)xv.y, (__bf16)xv.z, (__bf16)xv.w };
        *(bf16x4*)&As[1][r][c4] = o1;
    }
    __syncthreads();

    int lane = tid & 63;
    int wv   = tid >> 6;
    int rb   = wv * 16;
    int mrow = lane & 15;
    int koff = (lane >> 4) * 8;

    floatx4 acc[8];
#pragma unroll
    for (int i = 0; i < 8; i++) acc[i] = (floatx4){0.f, 0.f, 0.f, 0.f};

    const __bf16* Ws[2] = {Wl, Wr};
#pragma unroll
    for (int m = 0; m < 2; m++) {
#pragma unroll
        for (int kc = 0; kc < 4; kc++) {
            bf16x8 afrag = *(const bf16x8*)&As[m][rb + mrow][kc * 32 + koff];
#pragma unroll
            for (int ct = 0; ct < 8; ct++) {
                bf16x8 bfrag = *(const bf16x8*)(Ws[m] + (size_t)(ct * 16 + mrow) * DD + kc * 32 + koff);
                acc[ct] = __builtin_amdgcn_mfma_f32_16x16x32_bf16(afrag, bfrag, acc[ct], 0, 0, 0);
            }
        }
    }

    int orow = rb + (lane >> 4) * 4;
#pragma unroll
    for (int ct = 0; ct < 8; ct++) {
        int col = ct * 16 + mrow;
        float bb = bl[col];
#pragma unroll
        for (int r = 0; r < 4; r++) {
            int grow = row0 + orow + r;
            if (grow < M) {
                float v = acc[ct][r] + bb;
                v = (v > 0.f) ? v : expm1f(v);
                out[(size_t)grow * DD + col] = v;
            }
        }
    }
}

// ---------------------------------------------------------------------------
__global__ __launch_bounds__(256) void bn_stats(
    const float* __restrict__ x, int M,
    float* __restrict__ mout, float* __restrict__ rout)
{
    int n   = blockIdx.x;
    int tid = threadIdx.x;
    float s = 0.f, s2 = 0.f;
    for (int i = tid; i < M; i += 256) {
        float v = x[(size_t)i * DD + n];
        s += v; s2 += v * v;
    }
    __shared__ float ls[256], ls2[256];
    ls[tid] = s; ls2[tid] = s2;
    __syncthreads();
    for (int ofs = 128; ofs > 0; ofs >>= 1) {
        if (tid < ofs) { ls[tid] += ls[tid + ofs]; ls2[tid] += ls2[tid + ofs]; }
        __syncthreads();
    }
    if (tid == 0) {
        float m = ls[0] / (float)M;
        float v = ls2[0] / (float)M - m * m;
        mout[n] = m;
        rout[n] = rsqrtf(v + 1e-5f);
    }
}

__global__ __launch_bounds__(256) void bn_norm(
    const float* __restrict__ x,
    const float* __restrict__ m,
    const float* __restrict__ r,
    const float* __restrict__ g,
    const float* __restrict__ b,
    float* __restrict__ out,
    int M)
{
    int i = blockIdx.x * 256 + threadIdx.x;
    if (i >= M * 32) return;
    int row = i >> 5;
    int c4  = (i & 31) << 2;
    floatx4 v = *(const floatx4*)(x + (size_t)row * DD + c4);
    floatx4 o;
    o.x = (v.x - m[c4 + 0]) * r[c4 + 0] * g[c4 + 0] + b[c4 + 0];
    o.y = (v.y - m[c4 + 1]) * r[c4 + 1] * g[c4 + 1] + b[c4 + 1];
    o.z = (v.z - m[c4 + 2]) * r[c4 + 2] * g[c4 + 2] + b[c4 + 2];
    o.w = (v.w - m[c4 + 3]) * r[c4 + 3] * g[c4 + 3] + b[c4 + 3];
    *(floatx4*)(out + (size_t)row * DD + c4) = o;
}

// ---------------------------------------------------------------------------
extern "C" void kernel_launch(void* const* d_in, const int* in_sizes, int n_in,
                              void* d_out, int out_size, void* d_ws, size_t ws_size,
                              hipStream_t stream)
{
    const float* x_student = (const float*)d_in[0];
    const float* x_item    = (const float*)d_in[1];
    const float* Wl_ri     = (const float*)d_in[2];
    const float* bl_ri     = (const float*)d_in[3];
    const float* Wr_ri     = (const float*)d_in[4];
    const float* Wl_rs     = (const float*)d_in[5];
    const float* bl_rs     = (const float*)d_in[6];
    const float* Wr_rs     = (const float*)d_in[7];
    const float* W_p       = (const float*)d_in[8];
    const float* b_p       = (const float*)d_in[9];
    const float* bn_g      = (const float*)d_in[10];
    const float* bn_b      = (const float*)d_in[11];
    const int* resp_src = (const int*)d_in[12];
    const int* resp_dst = (const int*)d_in[13];
    const int* rev_src  = (const int*)d_in[14];
    const int* rev_dst  = (const int*)d_in[15];
    const int* prec_src = (const int*)d_in[16];
    const int* prec_dst = (const int*)d_in[17];

    // ---- workspace (~122 MB) ----
    char* ws = (char*)d_ws;
    size_t off = 0;
    auto alloc = [&](size_t bytes) -> void* {
        void* p = ws + off;
        off += (bytes + 1023) & ~(size_t)1023;
        return p;
    };
    // zeroed region (one small memset per call): CSR counts + totals
    int* cnt_r  = (int*)alloc(NIi * 4);
    int* cnt_v  = (int*)alloc(NSs * 4);
    int* cnt_p  = (int*)alloc(NSs * 4);
    int* totals = (int*)alloc(3 * 4);
    size_t zero_bytes = off;                        // ~0.88 MB
    // CSR arrays (fully overwritten each call)
    int* start_r = (int*)alloc(NIi * 4);
    int* fill_r  = (int*)alloc(NIi * 4);
    int* start_v = (int*)alloc(NSs * 4);
    int* fill_v  = (int*)alloc(NSs * 4);
    int* start_p = (int*)alloc(NSs * 4);
    int* fill_p  = (int*)alloc(NSs * 4);
    int* eidx_r  = (int*)alloc((size_t)E1e * 4);
    int* eidx_v  = (int*)alloc((size_t)E1e * 4);
    int* eidx_p  = (int*)alloc((size_t)E2e * 4);
    // aggregation buffers
    float* agg_s = (float*)alloc((size_t)NSs * DD * 4);   // 51.2 MB
    float* sim_s = (float*)alloc((size_t)NSs * DD * 4);   // 51.2 MB
    float* agg_i = (float*)alloc((size_t)NIi * DD * 4);   // 10.24 MB
    __bf16* wbf  = (__bf16*)alloc((size_t)5 * 32768 * 2);
    float* bn_m  = (float*)alloc(512);
    float* bn_r  = (float*)alloc(512);
    // xi_tmp aliases agg_s: agg_s is consumed by gemm_stu BEFORE gemm_item
    // writes xi_tmp, and xi_tmp is consumed by bn_* before the next layer's
    // gather rewrites agg_s.
    float* xi_tmp = agg_s;
    (void)ws_size; (void)in_sizes; (void)n_in; (void)out_size;

    // Output f32; layer-1 state lives in d_out, overwritten in-place by layer 2.
    float* out_xi = (float*)d_out;                    // xi_1 then xi_2
    float* out_xs = out_xi + (size_t)NIi * DD;        // xs_1 then xs_2

    const int he1 = (E1e + 255) / 256, he2 = (E2e + 255) / 256;
    const int tni = (NIi + 255) / 256, tns = (NSs + 255) / 256;
    const int g_i = (int)(((long)NIi * 64 + 255) / 256);
    const int g_s = (int)(((long)NSs * 64 + 255) / 256);
    const int gi_blocks  = (NIi + BM - 1) / BM;
    const int gs_blocks  = (NSs + BM - 1) / BM;
    const int bnn_blocks = (NIi * 32 + 255) / 256;

    cvt_weights<<<640, 256, 0, stream>>>(Wl_ri, Wr_ri, Wl_rs, Wr_rs, W_p, wbf);
    __bf16* wb_l_ri = wbf + 0 * 32768;
    __bf16* wb_r_ri = wbf + 1 * 32768;
    __bf16* wb_l_rs = wbf + 2 * 32768;
    __bf16* wb_r_rs = wbf + 3 * 32768;
    __bf16* wb_p    = wbf + 4 * 32768;

    // ---- CSR build (once per call, shared by both layers) ----
    hipMemsetAsync(ws, 0, zero_bytes, stream);
    hist_kernel<<<he1, 256, 0, stream>>>(resp_dst, cnt_r, E1e);
    hist_kernel<<<he1, 256, 0, stream>>>(rev_dst,  cnt_v, E1e);
    hist_kernel<<<he2, 256, 0, stream>>>(prec_dst, cnt_p, E2e);
    ticket_kernel<<<tni, 256, 0, stream>>>(cnt_r, start_r, fill_r, totals + 0, NIi);
    ticket_kernel<<<tns, 256, 0, stream>>>(cnt_v, start_v, fill_v, totals + 1, NSs);
    ticket_kernel<<<tns, 256, 0, stream>>>(cnt_p, start_p, fill_p, totals + 2, NSs);
    fill_kernel<<<he1, 256, 0, stream>>>(resp_src, resp_dst, fill_r, eidx_r, E1e);
    fill_kernel<<<he1, 256, 0, stream>>>(rev_src,  rev_dst,  fill_v, eidx_v, E1e);
    fill_kernel<<<he2, 256, 0, stream>>>(prec_src, prec_dst, fill_p, eidx_p, E2e);
    // after fill, fill_x[d] == end of segment d

    for (int l = 0; l < 2; l++) {
        const float* xs_cur = (l == 0) ? x_student : out_xs;
        const float* xi_cur = (l == 0) ? x_item    : out_xi;
        size_t wOfs = (size_t)l * DD * DD;
        size_t bOfs = (size_t)l * DD;

        gather_kernel<true><<<g_i, 256, 0, stream>>>(xs_cur, start_r, fill_r, eidx_r, agg_i, NIi);
        gather_kernel<true><<<g_s, 256, 0, stream>>>(xi_cur, start_v, fill_v, eidx_v, agg_s, NSs);
        gather_kernel<false><<<g_s, 256, 0, stream>>>(xs_cur, start_p, fill_p, eidx_p, sim_s, NSs);

        // student first (consumes agg_s before gemm_item reuses it as xi_tmp;
        // layer 2: xs_cur aliases out_xs, block-local rows only)
        gemm_stu<<<gs_blocks, 256, 0, stream>>>(agg_s, xs_cur, sim_s,
                                                wb_l_rs + wOfs, wb_r_rs + wOfs, wb_p + wOfs,
                                                bl_rs + bOfs, b_p + bOfs,
                                                out_xs, NSs);

        gemm_item<<<gi_blocks, 256, 0, stream>>>(agg_i, xi_cur,
                                                 wb_l_ri + wOfs, wb_r_ri + wOfs, bl_ri + bOfs,
                                                 xi_tmp, NIi);
        bn_stats<<<DD, 256, 0, stream>>>(xi_tmp, NIi, bn_m, bn_r);
        bn_norm<<<bnn_blocks, 256, 0, stream>>>(xi_tmp, bn_m, bn_r,
                                                bn_g + bOfs, bn_b + bOfs, out_xi, NIi);
    }
}